// Round 10
// baseline (3014.825 us; speedup 1.0000x reference)
//
#include <hip/hip_runtime.h>
#include <cstdint>
#include <cstddef>

typedef unsigned short u16;
typedef unsigned int u32;
typedef float f32x4 __attribute__((ext_vector_type(4)));
typedef __bf16 bf16x8 __attribute__((ext_vector_type(8)));

__device__ inline u16 f32_to_bf16(float f) {
  u32 u = __float_as_uint(f);
  u = (u + 0x7FFFu + ((u >> 16) & 1u)) >> 16;
  return (u16)u;
}
__device__ inline float bf16_to_f32(u16 h) {
  u32 u = (u32)h << 16;
  return __uint_as_float(u);
}

#define GLD16(src, dst)                                                        \
  __builtin_amdgcn_global_load_lds(                                            \
      (const __attribute__((address_space(1))) u32*)(src),                     \
      (__attribute__((address_space(3))) u32*)(dst), 16, 0, 0)

#define SBAR() __builtin_amdgcn_s_barrier()
#define SETPRIO(x) __builtin_amdgcn_s_setprio(x)
#define WAIT_LGKM0()                                                           \
  do {                                                                         \
    asm volatile("s_waitcnt lgkmcnt(0)" ::: "memory");                         \
    __builtin_amdgcn_sched_barrier(0);                                         \
  } while (0)
#define WAITV(N) asm volatile("s_waitcnt vmcnt(" #N ")" ::: "memory")
#define MFMA16(a, b, c) __builtin_amdgcn_mfma_f32_16x16x32_bf16(a, b, c, 0, 0, 0)

// ---- R1-proven tile layout: [rows][64 bf16] = 128B rows.
// LDS byte d holds global k-byte (d&127)^((row&7)<<4) of row d>>7. 0-conflict
// on write (linear 1KB/wave gld_lds) and fragment read (PMC, rounds 1,3,4).
// One staging op = 512 thr x 16B = 8KB = 64 rows.
__device__ inline void stage_op(const char* src, void* ldsBase, int rowBase,
                                int wave) {
  GLD16(src, (char*)ldsBase + rowBase * 128 + wave * 1024);
}

__device__ inline bf16x8 fragK(const u16* tile, int row, int ks, int p) {
  const int byte = row * 128 + (((ks << 6) + (p << 4)) ^ ((row & 7) << 4));
  return *(const bf16x8*)((const char*)tile + byte);
}

// ---------- x fp32 -> bf16 ----------
__global__ void k_convert_x(const float* __restrict__ x, u16* __restrict__ o) {
  const long i = (long)blockIdx.x * 256 + threadIdx.x;
  const float4 a = ((const float4*)x)[i * 2];
  const float4 b = ((const float4*)x)[i * 2 + 1];
  uint4 r;
  r.x = (u32)f32_to_bf16(a.x) | ((u32)f32_to_bf16(a.y) << 16);
  r.y = (u32)f32_to_bf16(a.z) | ((u32)f32_to_bf16(a.w) << 16);
  r.z = (u32)f32_to_bf16(b.x) | ((u32)f32_to_bf16(b.y) << 16);
  r.w = (u32)f32_to_bf16(b.z) | ((u32)f32_to_bf16(b.w) << 16);
  ((uint4*)o)[i] = r;
}

// ---------- dequant W[K][N] (int 0..15) -> out[N][K] bf16 (transposed) ------
__global__ __launch_bounds__(256) void k_dequant(const int* __restrict__ W,
                                                 const int* __restrict__ Z,
                                                 const float* __restrict__ S,
                                                 u16* __restrict__ out, int K,
                                                 int N) {
  __shared__ u16 ldsT[256 * 66];
  const int k0 = blockIdx.x * 64, n0 = blockIdx.y * 256;
  const int t = threadIdx.x;
  const int n4 = t & 63;
  const int kr = t >> 6;
  const int g = k0 >> 7;
  const int nb = n0 + n4 * 4;
  const int4 z4 = *(const int4*)(Z + (size_t)g * N + nb);
  const float4 s4 = *(const float4*)(S + (size_t)g * N + nb);
#pragma unroll
  for (int pass = 0; pass < 16; ++pass) {
    const int kl = kr + pass * 4;
    const int4 w4 = *(const int4*)(W + (size_t)(k0 + kl) * N + nb);
    ldsT[(n4 * 4 + 0) * 66 + kl] = f32_to_bf16((float)(w4.x - z4.x) * s4.x);
    ldsT[(n4 * 4 + 1) * 66 + kl] = f32_to_bf16((float)(w4.y - z4.y) * s4.y);
    ldsT[(n4 * 4 + 2) * 66 + kl] = f32_to_bf16((float)(w4.z - z4.z) * s4.z);
    ldsT[(n4 * 4 + 3) * 66 + kl] = f32_to_bf16((float)(w4.w - z4.w) * s4.w);
  }
  __syncthreads();
#pragma unroll
  for (int pass = 0; pass < 8; ++pass) {
    const int nl = pass * 32 + (t >> 3);
    const int kc = (t & 7) * 8;
    const u16* p = &ldsT[nl * 66 + kc];
    const u32 w0 = *(const u32*)(p + 0);
    const u32 w1 = *(const u32*)(p + 2);
    const u32 w2 = *(const u32*)(p + 4);
    const u32 w3 = *(const u32*)(p + 6);
    *(uint4*)(out + (size_t)(n0 + nl) * K + k0 + kc) =
        make_uint4(w0, w1, w2, w3);
  }
}

// ---------- unified 256x256 GEMM, R4 4-phase fine-interleaved schedule -----
// A[M][K] bf16 (k-contig), B[N][K] bf16 (n-major, k-contig).
// BM=BN=256 BK=64; 8 waves (2x4): per-wave 128 rows x 64 cols.
// Tile T staging issue order [A0,A128 | B0,B64 | B128,B192 | A64,A192],
// 2 ops/phase; counted vmcnt ledger verified (R4): P1-end vmcnt(6),
// P3-end vmcnt(4); tails 6->0, 4->2.
// EPI: 0 = store bf16 (gate -> g); 1 = load g, store silu(g)*acc bf16
// in-place (up); 2 = store f32 (down -> out).
template <int NKT, int EPI>
__global__ __launch_bounds__(512, 2) void k_gemm(const u16* __restrict__ A,
                                                 const u16* __restrict__ B,
                                                 void* __restrict__ OutP,
                                                 int ldOut) {
  __shared__ __align__(16) u16 lA[2][16384];
  __shared__ __align__(16) u16 lB[2][16384];
  const long STRB = (long)NKT * 128;  // row stride in bytes (K*2)
  const int m0 = blockIdx.x * 256, n0 = blockIdx.y * 256;
  const int tid = threadIdx.x, lane = tid & 63, wave = tid >> 6;
  const int p = lane >> 4, r16 = lane & 15;
  const int wr = wave >> 2, wc = wave & 3;

  const int srow = tid >> 3;
  const int skb = (((tid ^ (tid >> 3)) & 7) << 4);
  const char* baA = (const char*)A + (long)(m0 + srow) * STRB + skb;
  const char* baB = (const char*)B + (long)(n0 + srow) * STRB + skb;

#define ISS_A(kt2, rb) \
  stage_op(baA + (long)(rb)*STRB + (long)(kt2) * 128, lA[(kt2) & 1], rb, wave)
#define ISS_B(kt2, rb) \
  stage_op(baB + (long)(rb)*STRB + (long)(kt2) * 128, lB[(kt2) & 1], rb, wave)

  f32x4 acc[8][4];
  const f32x4 zero = {0.f, 0.f, 0.f, 0.f};
#pragma unroll
  for (int i = 0; i < 8; ++i)
#pragma unroll
    for (int j = 0; j < 4; ++j) acc[i][j] = zero;

  // prologue: kt0's 8 in consumed order + kt1's first pair; vmcnt(4)
  ISS_A(0, 0); ISS_A(0, 128); ISS_B(0, 0); ISS_B(0, 64);
  ISS_B(0, 128); ISS_B(0, 192); ISS_A(0, 64); ISS_A(0, 192);
  ISS_A(1, 0); ISS_A(1, 128);
  WAITV(4);
  SBAR();

  for (int kt = 0; kt < NKT; ++kt) {
    const int b = kt & 1;
    const u16* hA = lA[b];
    const u16* hB = lB[b];
    bf16x8 af[2][4], bfr[2][4];
    // ---- P0: read A(i0..3)+B(j0..1); stage kt+1's B-early ----
#pragma unroll
    for (int ks = 0; ks < 2; ++ks) {
#pragma unroll
      for (int ii = 0; ii < 4; ++ii)
        af[ks][ii] = fragK(hA, wr * 128 + ii * 16 + r16, ks, p);
#pragma unroll
      for (int j = 0; j < 2; ++j)
        bfr[ks][j] = fragK(hB, wc * 64 + j * 16 + r16, ks, p);
    }
    if (kt < NKT - 1) { ISS_B(kt + 1, 0); ISS_B(kt + 1, 64); }
    SBAR();
    WAIT_LGKM0();
    SETPRIO(1);
#pragma unroll
    for (int ks = 0; ks < 2; ++ks)
#pragma unroll
      for (int ii = 0; ii < 4; ++ii)
#pragma unroll
        for (int j = 0; j < 2; ++j)
          acc[ii][j] = MFMA16(af[ks][ii], bfr[ks][j], acc[ii][j]);
    SETPRIO(0);
    SBAR();
    // ---- P1: read B(j2..3); stage kt+1's B-late ----
#pragma unroll
    for (int ks = 0; ks < 2; ++ks)
#pragma unroll
      for (int j = 2; j < 4; ++j)
        bfr[ks][j] = fragK(hB, wc * 64 + j * 16 + r16, ks, p);
    if (kt < NKT - 1) { ISS_B(kt + 1, 128); ISS_B(kt + 1, 192); }
    SBAR();
    WAIT_LGKM0();
    SETPRIO(1);
#pragma unroll
    for (int ks = 0; ks < 2; ++ks)
#pragma unroll
      for (int ii = 0; ii < 4; ++ii)
#pragma unroll
        for (int j = 2; j < 4; ++j)
          acc[ii][j] = MFMA16(af[ks][ii], bfr[ks][j], acc[ii][j]);
    SETPRIO(0);
    if (kt < NKT - 1) WAITV(6); else WAITV(0);  // kt's A64/A192 landed
    SBAR();
    // ---- P2: read A(i4..7) (last read of buf b); stage kt+1's A-late ----
#pragma unroll
    for (int ks = 0; ks < 2; ++ks)
#pragma unroll
      for (int ii = 0; ii < 4; ++ii)
        af[ks][ii] = fragK(hA, wr * 128 + 64 + ii * 16 + r16, ks, p);
    if (kt < NKT - 1) { ISS_A(kt + 1, 64); ISS_A(kt + 1, 192); }
    SBAR();
    WAIT_LGKM0();
    SETPRIO(1);
#pragma unroll
    for (int ks = 0; ks < 2; ++ks)
#pragma unroll
      for (int ii = 0; ii < 4; ++ii)
#pragma unroll
        for (int j = 0; j < 2; ++j)
          acc[4 + ii][j] = MFMA16(af[ks][ii], bfr[ks][j], acc[4 + ii][j]);
    SETPRIO(0);
    SBAR();
    // ---- P3: stage kt+2's A-early into buf b; MFMA i4..7 x j2..3 ----
    if (kt < NKT - 2) { ISS_A(kt + 2, 0); ISS_A(kt + 2, 128); }
    SBAR();
    SETPRIO(1);
#pragma unroll
    for (int ks = 0; ks < 2; ++ks)
#pragma unroll
      for (int ii = 0; ii < 4; ++ii)
#pragma unroll
        for (int j = 2; j < 4; ++j)
          acc[4 + ii][j] = MFMA16(af[ks][ii], bfr[ks][j], acc[4 + ii][j]);
    SETPRIO(0);
    if (kt < NKT - 2) WAITV(4);       // kt+1's first 6 landed
    else if (kt == NKT - 2) WAITV(2);
    SBAR();
  }
#undef ISS_A
#undef ISS_B

  // epilogue. C/D map: col=lane&15, row=(lane>>4)*4+reg.
#pragma unroll
  for (int i = 0; i < 8; ++i) {
    const int row = m0 + wr * 128 + i * 16 + p * 4;
#pragma unroll
    for (int j = 0; j < 4; ++j) {
      const int col = n0 + wc * 64 + j * 16 + r16;
      if constexpr (EPI == 0) {
        u16* dst = (u16*)OutP + (size_t)row * ldOut + col;
#pragma unroll
        for (int r = 0; r < 4; ++r)
          dst[(size_t)r * ldOut] = f32_to_bf16(acc[i][j][r]);
      } else if constexpr (EPI == 1) {
        u16* dst = (u16*)OutP + (size_t)row * ldOut + col;
#pragma unroll
        for (int r = 0; r < 4; ++r) {
          const float gv = bf16_to_f32(dst[(size_t)r * ldOut]);
          const float sv = gv / (1.f + __expf(-gv)) * acc[i][j][r];
          dst[(size_t)r * ldOut] = f32_to_bf16(sv);
        }
      } else {
        float* dst = (float*)OutP + (size_t)row * ldOut + col;
#pragma unroll
        for (int r = 0; r < 4; ++r) dst[(size_t)r * ldOut] = acc[i][j][r];
      }
    }
  }
}

// ---------- sentinel fill (ws too small diagnostic) ----------
__global__ void k_fill(float* o, long n, float v) {
  const long i = (long)blockIdx.x * 256 + threadIdx.x;
  if (i < n) o[i] = v;
}

extern "C" void kernel_launch(void* const* d_in, const int* in_sizes, int n_in,
                              void* d_out, int out_size, void* d_ws,
                              size_t ws_size, hipStream_t stream) {
  const float* x = (const float*)d_in[0];
  const int* gw = (const int*)d_in[1];
  const int* gz = (const int*)d_in[2];
  const float* gs = (const float*)d_in[3];
  const int* uw = (const int*)d_in[4];
  const int* uz = (const int*)d_in[5];
  const float* us = (const float*)d_in[6];
  const int* dw = (const int*)d_in[7];
  const int* dz = (const int*)d_in[8];
  const float* dsc = (const float*)d_in[9];
  float* out = (float*)d_out;

  // ws layout (bf16 elems): x | Wg | Wu | Wd | h  (654,311,424 B)
  const size_t NX = 33554432UL, NW = 58720256UL;
  const size_t need = 2UL * (NX + 3UL * NW + 117440512UL);
  if (ws_size < need) {
    k_fill<<<(out_size + 255) / 256, 256, 0, stream>>>(out, out_size, 1.0e6f);
    return;
  }
  u16* wsx = (u16*)d_ws;
  u16* wgq = wsx + NX;
  u16* wuq = wgq + NW;
  u16* wdq = wuq + NW;
  u16* wh = wdq + NW;

  dim3 dq1(64, 56);   // K=4096, N=14336
  dim3 dq2(224, 16);  // K=14336, N=4096
  dim3 gUp(32, 56);   // M=8192/256, N=14336/256
  dim3 gDn(32, 16);   // M=8192/256, N=4096/256

  // Order maximizes producer->consumer L3 adjacency (R9 lesson):
  // each GEMM's weight is dequantized immediately before it; h is written
  // immediately before down (Wd dequant hoisted to the front).
  k_convert_x<<<16384, 256, 0, stream>>>(x, wsx);
  k_dequant<<<dq2, 256, 0, stream>>>(dw, dz, dsc, wdq, 14336, 4096);
  // gate: g = x @ Wg -> wh (bf16)
  k_dequant<<<dq1, 256, 0, stream>>>(gw, gz, gs, wgq, 4096, 14336);
  k_gemm<64, 0><<<gUp, 512, 0, stream>>>(wsx, wgq, wh, 14336);
  // up (+fused silu-mul): h = silu(g) * (x @ Wu) -> wh in-place
  k_dequant<<<dq1, 256, 0, stream>>>(uw, uz, us, wuq, 4096, 14336);
  k_gemm<64, 1><<<gUp, 512, 0, stream>>>(wsx, wuq, wh, 14336);
  // down: out = h @ Wd (f32); h written by the immediately-preceding kernel
  k_gemm<224, 2><<<gDn, 512, 0, stream>>>(wh, wdq, out, 4096);
}

// Round 11
// 2602.266 us; speedup vs baseline: 1.1585x; 1.1585x over previous
//
#include <hip/hip_runtime.h>
#include <cstdint>
#include <cstddef>

typedef unsigned short u16;
typedef unsigned int u32;
typedef float f32x4 __attribute__((ext_vector_type(4)));
typedef __bf16 bf16x8 __attribute__((ext_vector_type(8)));

__device__ inline u16 f32_to_bf16(float f) {
  u32 u = __float_as_uint(f);
  u = (u + 0x7FFFu + ((u >> 16) & 1u)) >> 16;
  return (u16)u;
}

#define GLD16(src, dst)                                                        \
  __builtin_amdgcn_global_load_lds(                                            \
      (const __attribute__((address_space(1))) u32*)(src),                     \
      (__attribute__((address_space(3))) u32*)(dst), 16, 0, 0)

#define SBAR() __builtin_amdgcn_s_barrier()
#define SETPRIO(x) __builtin_amdgcn_s_setprio(x)
#define WAIT_LGKM0()                                                           \
  do {                                                                         \
    asm volatile("s_waitcnt lgkmcnt(0)" ::: "memory");                         \
    __builtin_amdgcn_sched_barrier(0);                                         \
  } while (0)
#define WAITV(N) asm volatile("s_waitcnt vmcnt(" #N ")" ::: "memory")
#define MFMA16(a, b, c) __builtin_amdgcn_mfma_f32_16x16x32_bf16(a, b, c, 0, 0, 0)

// ---- R1-proven tile layout: [rows][64 bf16] = 128B rows.
// LDS byte d holds global k-byte (d&127)^((row&7)<<4) of row d>>7. 0-conflict
// on write (linear 1KB/wave gld_lds) and fragment read (PMC, rounds 1,3,4).
// One staging op = 512 thr x 16B = 8KB = 64 rows.
__device__ inline void stage_op(const char* src, void* ldsBase, int rowBase,
                                int wave) {
  GLD16(src, (char*)ldsBase + rowBase * 128 + wave * 1024);
}

__device__ inline bf16x8 fragK(const u16* tile, int row, int ks, int p) {
  const int byte = row * 128 + (((ks << 6) + (p << 4)) ^ ((row & 7) << 4));
  return *(const bf16x8*)((const char*)tile + byte);
}

// ---------- x fp32 -> bf16 ----------
__global__ void k_convert_x(const float* __restrict__ x, u16* __restrict__ o) {
  const long i = (long)blockIdx.x * 256 + threadIdx.x;
  const float4 a = ((const float4*)x)[i * 2];
  const float4 b = ((const float4*)x)[i * 2 + 1];
  uint4 r;
  r.x = (u32)f32_to_bf16(a.x) | ((u32)f32_to_bf16(a.y) << 16);
  r.y = (u32)f32_to_bf16(a.z) | ((u32)f32_to_bf16(a.w) << 16);
  r.z = (u32)f32_to_bf16(b.x) | ((u32)f32_to_bf16(b.y) << 16);
  r.w = (u32)f32_to_bf16(b.z) | ((u32)f32_to_bf16(b.w) << 16);
  ((uint4*)o)[i] = r;
}

// ---------- dequant W[K][N] (int 0..15) -> out[N][K] bf16 (transposed) ------
__global__ __launch_bounds__(256) void k_dequant(const int* __restrict__ W,
                                                 const int* __restrict__ Z,
                                                 const float* __restrict__ S,
                                                 u16* __restrict__ out, int K,
                                                 int N) {
  __shared__ u16 ldsT[256 * 66];
  const int k0 = blockIdx.x * 64, n0 = blockIdx.y * 256;
  const int t = threadIdx.x;
  const int n4 = t & 63;
  const int kr = t >> 6;
  const int g = k0 >> 7;
  const int nb = n0 + n4 * 4;
  const int4 z4 = *(const int4*)(Z + (size_t)g * N + nb);
  const float4 s4 = *(const float4*)(S + (size_t)g * N + nb);
#pragma unroll
  for (int pass = 0; pass < 16; ++pass) {
    const int kl = kr + pass * 4;
    const int4 w4 = *(const int4*)(W + (size_t)(k0 + kl) * N + nb);
    ldsT[(n4 * 4 + 0) * 66 + kl] = f32_to_bf16((float)(w4.x - z4.x) * s4.x);
    ldsT[(n4 * 4 + 1) * 66 + kl] = f32_to_bf16((float)(w4.y - z4.y) * s4.y);
    ldsT[(n4 * 4 + 2) * 66 + kl] = f32_to_bf16((float)(w4.z - z4.z) * s4.z);
    ldsT[(n4 * 4 + 3) * 66 + kl] = f32_to_bf16((float)(w4.w - z4.w) * s4.w);
  }
  __syncthreads();
#pragma unroll
  for (int pass = 0; pass < 8; ++pass) {
    const int nl = pass * 32 + (t >> 3);
    const int kc = (t & 7) * 8;
    const u16* p = &ldsT[nl * 66 + kc];
    const u32 w0 = *(const u32*)(p + 0);
    const u32 w1 = *(const u32*)(p + 2);
    const u32 w2 = *(const u32*)(p + 4);
    const u32 w3 = *(const u32*)(p + 6);
    *(uint4*)(out + (size_t)(n0 + nl) * K + k0 + kc) =
        make_uint4(w0, w1, w2, w3);
  }
}

// ---------- fused gate/up GEMM, 4-phase fine-interleaved schedule ----------
// X[8192][4096] bf16, WG/WU [14336][4096] bf16 (n-major), Hout[8192][14336]
// BM=256 BN=128 BK=64; 8 waves (2x4): per-wave 128 rows x 32 cols x {G,U}.
// Tile T's 8 staging ops issued 2/phase over [T-2.P3, T-1.P0, T-1.P1, T-1.P2]
// in first-consumed order [A0,A128 | G0,G64 | U0,U64 | A64,A192].
// R11: epilogue h-stores are NON-TEMPORAL -- h (235 MB) is not re-read until
// k_gemm_down; letting it allocate in L3 evicted X each round (R4 PMC:
// FETCH 1.41 GB vs 301 MB ideal = X re-fetched ~14x).
__global__ __launch_bounds__(512, 2) void k_gemm_gu(
    const u16* __restrict__ X, const u16* __restrict__ WG,
    const u16* __restrict__ WU, u16* __restrict__ Hout) {
  __shared__ __align__(16) u16 lA[2][16384];  // 2 x 256 rows x 64 k
  __shared__ __align__(16) u16 lG[2][8192];   // 2 x 128 rows x 64 k
  __shared__ __align__(16) u16 lU[2][8192];
  const int NKT = 64;
  const int m0 = blockIdx.x * 256, n0 = blockIdx.y * 128;
  const int tid = threadIdx.x, lane = tid & 63, wave = tid >> 6;
  const int p = lane >> 4, r16 = lane & 15;
  const int wr = wave >> 2, wc = wave & 3;

  const int srow = tid >> 3;                       // 0..63
  const int skb = (((tid ^ (tid >> 3)) & 7) << 4); // pre-swizzled k-byte
  const char* baA = (const char*)X + (long)(m0 + srow) * 8192 + skb;
  const char* baG = (const char*)WG + (long)(n0 + srow) * 8192 + skb;
  const char* baU = (const char*)WU + (long)(n0 + srow) * 8192 + skb;

#define ISS_A(kt2, rb) \
  stage_op(baA + (long)(rb) * 8192 + (long)(kt2) * 128, lA[(kt2) & 1], rb, wave)
#define ISS_G(kt2, rb) \
  stage_op(baG + (long)(rb) * 8192 + (long)(kt2) * 128, lG[(kt2) & 1], rb, wave)
#define ISS_U(kt2, rb) \
  stage_op(baU + (long)(rb) * 8192 + (long)(kt2) * 128, lU[(kt2) & 1], rb, wave)

  f32x4 aG[8][2], aU[8][2];
  const f32x4 zero = {0.f, 0.f, 0.f, 0.f};
#pragma unroll
  for (int i = 0; i < 8; ++i)
#pragma unroll
    for (int j = 0; j < 2; ++j) {
      aG[i][j] = zero;
      aU[i][j] = zero;
    }

  // prologue: kt0's 8 ops in consumed order + kt1's first pair; vmcnt(6)
  ISS_A(0, 0); ISS_A(0, 128); ISS_G(0, 0); ISS_G(0, 64);
  ISS_U(0, 0); ISS_U(0, 64); ISS_A(0, 64); ISS_A(0, 192);
  ISS_A(1, 0); ISS_A(1, 128);
  WAITV(6);
  SBAR();

  for (int kt = 0; kt < NKT; ++kt) {
    const int b = kt & 1;
    const u16* hA = lA[b];
    const u16* hG = lG[b];
    const u16* hU = lU[b];
    bf16x8 af[2][4], gf[2][2], uf[2][2];
    // ---- P0: read A(i0..3)+G; stage kt+1's G; MFMA aG i0..3 ----
#pragma unroll
    for (int ks = 0; ks < 2; ++ks) {
#pragma unroll
      for (int ii = 0; ii < 4; ++ii)
        af[ks][ii] = fragK(hA, wr * 128 + ii * 16 + r16, ks, p);
#pragma unroll
      for (int j = 0; j < 2; ++j)
        gf[ks][j] = fragK(hG, wc * 32 + j * 16 + r16, ks, p);
    }
    if (kt < NKT - 1) { ISS_G(kt + 1, 0); ISS_G(kt + 1, 64); }
    SBAR();
    WAIT_LGKM0();
    SETPRIO(1);
#pragma unroll
    for (int ks = 0; ks < 2; ++ks)
#pragma unroll
      for (int ii = 0; ii < 4; ++ii)
#pragma unroll
        for (int j = 0; j < 2; ++j)
          aG[ii][j] = MFMA16(af[ks][ii], gf[ks][j], aG[ii][j]);
    SETPRIO(0);
    if (kt < NKT - 1) WAITV(6); else WAITV(2);  // kt's U landed
    SBAR();
    // ---- P1: read U; stage kt+1's U; MFMA aU i0..3 ----
#pragma unroll
    for (int ks = 0; ks < 2; ++ks)
#pragma unroll
      for (int j = 0; j < 2; ++j)
        uf[ks][j] = fragK(hU, wc * 32 + j * 16 + r16, ks, p);
    if (kt < NKT - 1) { ISS_U(kt + 1, 0); ISS_U(kt + 1, 64); }
    SBAR();
    WAIT_LGKM0();
    SETPRIO(1);
#pragma unroll
    for (int ks = 0; ks < 2; ++ks)
#pragma unroll
      for (int ii = 0; ii < 4; ++ii)
#pragma unroll
        for (int j = 0; j < 2; ++j)
          aU[ii][j] = MFMA16(af[ks][ii], uf[ks][j], aU[ii][j]);
    SETPRIO(0);
    if (kt < NKT - 1) WAITV(6); else WAITV(0);  // kt's A64/A192 landed
    SBAR();
    // ---- P2: read A(i4..7) (last read of buf b); stage kt+1's A-late ----
#pragma unroll
    for (int ks = 0; ks < 2; ++ks)
#pragma unroll
      for (int ii = 0; ii < 4; ++ii)
        af[ks][ii] = fragK(hA, wr * 128 + 64 + ii * 16 + r16, ks, p);
    if (kt < NKT - 1) { ISS_A(kt + 1, 64); ISS_A(kt + 1, 192); }
    SBAR();
    WAIT_LGKM0();
    SETPRIO(1);
#pragma unroll
    for (int ks = 0; ks < 2; ++ks)
#pragma unroll
      for (int ii = 0; ii < 4; ++ii)
#pragma unroll
        for (int j = 0; j < 2; ++j)
          aG[4 + ii][j] = MFMA16(af[ks][ii], gf[ks][j], aG[4 + ii][j]);
    SETPRIO(0);
    SBAR();
    // ---- P3: stage kt+2's A-early into buf b (reads drained); MFMA aU ----
    if (kt < NKT - 2) { ISS_A(kt + 2, 0); ISS_A(kt + 2, 128); }
    SBAR();
    SETPRIO(1);
#pragma unroll
    for (int ks = 0; ks < 2; ++ks)
#pragma unroll
      for (int ii = 0; ii < 4; ++ii)
#pragma unroll
        for (int j = 0; j < 2; ++j)
          aU[4 + ii][j] = MFMA16(af[ks][ii], uf[ks][j], aU[4 + ii][j]);
    SETPRIO(0);
    if (kt < NKT - 2) WAITV(6);       // kt+1's first 4 landed
    else if (kt == NKT - 2) WAITV(4);
    SBAR();
  }
#undef ISS_A
#undef ISS_G
#undef ISS_U

  // epilogue: silu(g)*u -> bf16, NON-TEMPORAL stores (h not re-read soon).
  // C/D map: col=lane&15, row=(lane>>4)*4+reg.
#pragma unroll
  for (int i = 0; i < 8; ++i) {
    const int row = m0 + wr * 128 + i * 16 + p * 4;
#pragma unroll
    for (int j = 0; j < 2; ++j) {
      const int col = n0 + wc * 32 + j * 16 + r16;
      u16* dst = Hout + (size_t)row * 14336 + col;
#pragma unroll
      for (int r = 0; r < 4; ++r) {
        const float gv = aG[i][j][r], uv = aU[i][j][r];
        const float sv = gv / (1.f + __expf(-gv)) * uv;
        __builtin_nontemporal_store(f32_to_bf16(sv), &dst[(size_t)r * 14336]);
      }
    }
  }
}

// ---------- down GEMM, 4-phase fine-interleaved: out = h @ Wd (f32) ----------
// Hin[8192][14336] bf16, WD[4096][14336] bf16 (n-major), Out[8192][4096] f32
// BM=BN=256 BK=64; 8 waves (2x4): per-wave 128 rows x 64 cols.
// Tile T issue order [A0,A128 | B0,B64 | B128,B192 | A64,A192].
// R11: out-stores non-temporal (out is never re-read on device).
__global__ __launch_bounds__(512, 2) void k_gemm_down(
    const u16* __restrict__ Hin, const u16* __restrict__ WD,
    float* __restrict__ Out) {
  __shared__ __align__(16) u16 lA[2][16384];
  __shared__ __align__(16) u16 lB[2][16384];
  const int NKT = 224;
  const int m0 = blockIdx.x * 256, n0 = blockIdx.y * 256;
  const int tid = threadIdx.x, lane = tid & 63, wave = tid >> 6;
  const int p = lane >> 4, r16 = lane & 15;
  const int wr = wave >> 2, wc = wave & 3;

  const int srow = tid >> 3;
  const int skb = (((tid ^ (tid >> 3)) & 7) << 4);
  const char* baA = (const char*)Hin + (long)(m0 + srow) * 28672 + skb;
  const char* baB = (const char*)WD + (long)(n0 + srow) * 28672 + skb;

#define ISS_A(kt2, rb) \
  stage_op(baA + (long)(rb) * 28672 + (long)(kt2) * 128, lA[(kt2) & 1], rb, wave)
#define ISS_B(kt2, rb) \
  stage_op(baB + (long)(rb) * 28672 + (long)(kt2) * 128, lB[(kt2) & 1], rb, wave)

  f32x4 acc[8][4];
  const f32x4 zero = {0.f, 0.f, 0.f, 0.f};
#pragma unroll
  for (int i = 0; i < 8; ++i)
#pragma unroll
    for (int j = 0; j < 4; ++j) acc[i][j] = zero;

  // prologue: kt0's 8 in consumed order + kt1's first pair; vmcnt(4)
  ISS_A(0, 0); ISS_A(0, 128); ISS_B(0, 0); ISS_B(0, 64);
  ISS_B(0, 128); ISS_B(0, 192); ISS_A(0, 64); ISS_A(0, 192);
  ISS_A(1, 0); ISS_A(1, 128);
  WAITV(4);
  SBAR();

  for (int kt = 0; kt < NKT; ++kt) {
    const int b = kt & 1;
    const u16* hA = lA[b];
    const u16* hB = lB[b];
    bf16x8 af[2][4], bfr[2][4];
    // ---- P0: read A(i0..3)+B(j0..1); stage kt+1's B-early ----
#pragma unroll
    for (int ks = 0; ks < 2; ++ks) {
#pragma unroll
      for (int ii = 0; ii < 4; ++ii)
        af[ks][ii] = fragK(hA, wr * 128 + ii * 16 + r16, ks, p);
#pragma unroll
      for (int j = 0; j < 2; ++j)
        bfr[ks][j] = fragK(hB, wc * 64 + j * 16 + r16, ks, p);
    }
    if (kt < NKT - 1) { ISS_B(kt + 1, 0); ISS_B(kt + 1, 64); }
    SBAR();
    WAIT_LGKM0();
    SETPRIO(1);
#pragma unroll
    for (int ks = 0; ks < 2; ++ks)
#pragma unroll
      for (int ii = 0; ii < 4; ++ii)
#pragma unroll
        for (int j = 0; j < 2; ++j)
          acc[ii][j] = MFMA16(af[ks][ii], bfr[ks][j], acc[ii][j]);
    SETPRIO(0);
    SBAR();
    // ---- P1: read B(j2..3); stage kt+1's B-late ----
#pragma unroll
    for (int ks = 0; ks < 2; ++ks)
#pragma unroll
      for (int j = 2; j < 4; ++j)
        bfr[ks][j] = fragK(hB, wc * 64 + j * 16 + r16, ks, p);
    if (kt < NKT - 1) { ISS_B(kt + 1, 128); ISS_B(kt + 1, 192); }
    SBAR();
    WAIT_LGKM0();
    SETPRIO(1);
#pragma unroll
    for (int ks = 0; ks < 2; ++ks)
#pragma unroll
      for (int ii = 0; ii < 4; ++ii)
#pragma unroll
        for (int j = 2; j < 4; ++j)
          acc[ii][j] = MFMA16(af[ks][ii], bfr[ks][j], acc[ii][j]);
    SETPRIO(0);
    if (kt < NKT - 1) WAITV(6); else WAITV(0);  // kt's A64/A192 landed
    SBAR();
    // ---- P2: read A(i4..7) (last read of buf b); stage kt+1's A-late ----
#pragma unroll
    for (int ks = 0; ks < 2; ++ks)
#pragma unroll
      for (int ii = 0; ii < 4; ++ii)
        af[ks][ii] = fragK(hA, wr * 128 + 64 + ii * 16 + r16, ks, p);
    if (kt < NKT - 1) { ISS_A(kt + 1, 64); ISS_A(kt + 1, 192); }
    SBAR();
    WAIT_LGKM0();
    SETPRIO(1);
#pragma unroll
    for (int ks = 0; ks < 2; ++ks)
#pragma unroll
      for (int ii = 0; ii < 4; ++ii)
#pragma unroll
        for (int j = 0; j < 2; ++j)
          acc[4 + ii][j] = MFMA16(af[ks][ii], bfr[ks][j], acc[4 + ii][j]);
    SETPRIO(0);
    SBAR();
    // ---- P3: stage kt+2's A-early into buf b; MFMA i4..7 x j2..3 ----
    if (kt < NKT - 2) { ISS_A(kt + 2, 0); ISS_A(kt + 2, 128); }
    SBAR();
    SETPRIO(1);
#pragma unroll
    for (int ks = 0; ks < 2; ++ks)
#pragma unroll
      for (int ii = 0; ii < 4; ++ii)
#pragma unroll
        for (int j = 2; j < 4; ++j)
          acc[4 + ii][j] = MFMA16(af[ks][ii], bfr[ks][j], acc[4 + ii][j]);
    SETPRIO(0);
    if (kt < NKT - 2) WAITV(4);       // kt+1's first 6 landed
    else if (kt == NKT - 2) WAITV(2);
    SBAR();
  }
#undef ISS_A
#undef ISS_B

#pragma unroll
  for (int i = 0; i < 8; ++i) {
    const int row = m0 + wr * 128 + i * 16 + p * 4;
#pragma unroll
    for (int j = 0; j < 4; ++j) {
      const int col = n0 + wc * 64 + j * 16 + r16;
      float* dst = Out + (size_t)row * 4096 + col;
#pragma unroll
      for (int r = 0; r < 4; ++r)
        __builtin_nontemporal_store(acc[i][j][r], &dst[(size_t)r * 4096]);
    }
  }
}

// ---------- sentinel fill (ws too small diagnostic) ----------
__global__ void k_fill(float* o, long n, float v) {
  const long i = (long)blockIdx.x * 256 + threadIdx.x;
  if (i < n) o[i] = v;
}

extern "C" void kernel_launch(void* const* d_in, const int* in_sizes, int n_in,
                              void* d_out, int out_size, void* d_ws,
                              size_t ws_size, hipStream_t stream) {
  const float* x = (const float*)d_in[0];
  const int* gw = (const int*)d_in[1];
  const int* gz = (const int*)d_in[2];
  const float* gs = (const float*)d_in[3];
  const int* uw = (const int*)d_in[4];
  const int* uz = (const int*)d_in[5];
  const float* us = (const float*)d_in[6];
  const int* dw = (const int*)d_in[7];
  const int* dz = (const int*)d_in[8];
  const float* dsc = (const float*)d_in[9];
  float* out = (float*)d_out;

  const size_t NX = 33554432UL, NW = 58720256UL;
  const size_t need = 2UL * (NX + 3UL * NW + 117440512UL);
  if (ws_size < need) {
    k_fill<<<(out_size + 255) / 256, 256, 0, stream>>>(out, out_size, 1.0e6f);
    return;
  }
  u16* wsx = (u16*)d_ws;
  u16* wgq = wsx + NX;
  u16* wuq = wgq + NW;
  u16* wdq = wuq + NW;
  u16* wh = wdq + NW;

  k_convert_x<<<16384, 256, 0, stream>>>(x, wsx);
  dim3 dq1(64, 56);
  k_dequant<<<dq1, 256, 0, stream>>>(gw, gz, gs, wgq, 4096, 14336);
  k_dequant<<<dq1, 256, 0, stream>>>(uw, uz, us, wuq, 4096, 14336);
  dim3 dq2(224, 16);
  k_dequant<<<dq2, 256, 0, stream>>>(dw, dz, dsc, wdq, 14336, 4096);
  dim3 g1(32, 112);
  k_gemm_gu<<<g1, 512, 0, stream>>>(wsx, wgq, wuq, wh);
  dim3 g2(32, 16);
  k_gemm_down<<<g2, 512, 0, stream>>>(wh, wdq, out);
}

// Round 12
// 2567.914 us; speedup vs baseline: 1.1740x; 1.0134x over previous
//
#include <hip/hip_runtime.h>
#include <cstdint>
#include <cstddef>

typedef unsigned short u16;
typedef unsigned int u32;
typedef float f32x4 __attribute__((ext_vector_type(4)));
typedef __bf16 bf16x8 __attribute__((ext_vector_type(8)));

__device__ inline u16 f32_to_bf16(float f) {
  u32 u = __float_as_uint(f);
  u = (u + 0x7FFFu + ((u >> 16) & 1u)) >> 16;
  return (u16)u;
}

#define GLD16(src, dst)                                                        \
  __builtin_amdgcn_global_load_lds(                                            \
      (const __attribute__((address_space(1))) u32*)(src),                     \
      (__attribute__((address_space(3))) u32*)(dst), 16, 0, 0)

#define SBAR() __builtin_amdgcn_s_barrier()
#define SETPRIO(x) __builtin_amdgcn_s_setprio(x)
#define WAIT_LGKM0()                                                           \
  do {                                                                         \
    asm volatile("s_waitcnt lgkmcnt(0)" ::: "memory");                         \
    __builtin_amdgcn_sched_barrier(0);                                         \
  } while (0)
#define WAITV(N) asm volatile("s_waitcnt vmcnt(" #N ")" ::: "memory")
#define MFMA16(a, b, c) __builtin_amdgcn_mfma_f32_16x16x32_bf16(a, b, c, 0, 0, 0)

// ---- R1-proven tile layout: [rows][64 bf16] = 128B rows.
// LDS byte d holds global k-byte (d&127)^((row&7)<<4) of row d>>7. 0-conflict
// on write (linear 1KB/wave gld_lds) and fragment read (PMC, rounds 1,3,4).
// One staging op = 512 thr x 16B = 8KB = 64 rows.
__device__ inline void stage_op(const char* src, void* ldsBase, int rowBase,
                                int wave) {
  GLD16(src, (char*)ldsBase + rowBase * 128 + wave * 1024);
}

__device__ inline bf16x8 fragK(const u16* tile, int row, int ks, int p) {
  const int byte = row * 128 + (((ks << 6) + (p << 4)) ^ ((row & 7) << 4));
  return *(const bf16x8*)((const char*)tile + byte);
}

// ---------- x fp32 -> bf16 ----------
__global__ void k_convert_x(const float* __restrict__ x, u16* __restrict__ o) {
  const long i = (long)blockIdx.x * 256 + threadIdx.x;
  const float4 a = ((const float4*)x)[i * 2];
  const float4 b = ((const float4*)x)[i * 2 + 1];
  uint4 r;
  r.x = (u32)f32_to_bf16(a.x) | ((u32)f32_to_bf16(a.y) << 16);
  r.y = (u32)f32_to_bf16(a.z) | ((u32)f32_to_bf16(a.w) << 16);
  r.z = (u32)f32_to_bf16(b.x) | ((u32)f32_to_bf16(b.y) << 16);
  r.w = (u32)f32_to_bf16(b.z) | ((u32)f32_to_bf16(b.w) << 16);
  ((uint4*)o)[i] = r;
}

// ---------- dequant W[K][N] (int 0..15) -> out[N][K] bf16 (transposed) ------
__global__ __launch_bounds__(256) void k_dequant(const int* __restrict__ W,
                                                 const int* __restrict__ Z,
                                                 const float* __restrict__ S,
                                                 u16* __restrict__ out, int K,
                                                 int N) {
  __shared__ u16 ldsT[256 * 66];
  const int k0 = blockIdx.x * 64, n0 = blockIdx.y * 256;
  const int t = threadIdx.x;
  const int n4 = t & 63;
  const int kr = t >> 6;
  const int g = k0 >> 7;
  const int nb = n0 + n4 * 4;
  const int4 z4 = *(const int4*)(Z + (size_t)g * N + nb);
  const float4 s4 = *(const float4*)(S + (size_t)g * N + nb);
#pragma unroll
  for (int pass = 0; pass < 16; ++pass) {
    const int kl = kr + pass * 4;
    const int4 w4 = *(const int4*)(W + (size_t)(k0 + kl) * N + nb);
    ldsT[(n4 * 4 + 0) * 66 + kl] = f32_to_bf16((float)(w4.x - z4.x) * s4.x);
    ldsT[(n4 * 4 + 1) * 66 + kl] = f32_to_bf16((float)(w4.y - z4.y) * s4.y);
    ldsT[(n4 * 4 + 2) * 66 + kl] = f32_to_bf16((float)(w4.z - z4.z) * s4.z);
    ldsT[(n4 * 4 + 3) * 66 + kl] = f32_to_bf16((float)(w4.w - z4.w) * s4.w);
  }
  __syncthreads();
#pragma unroll
  for (int pass = 0; pass < 8; ++pass) {
    const int nl = pass * 32 + (t >> 3);
    const int kc = (t & 7) * 8;
    const u16* p = &ldsT[nl * 66 + kc];
    const u32 w0 = *(const u32*)(p + 0);
    const u32 w1 = *(const u32*)(p + 2);
    const u32 w2 = *(const u32*)(p + 4);
    const u32 w3 = *(const u32*)(p + 6);
    *(uint4*)(out + (size_t)(n0 + nl) * K + k0 + kc) =
        make_uint4(w0, w1, w2, w3);
  }
}

// ---------- fused gate/up GEMM, 4-phase, R12 two-wait ledger ----------
// X[8192][4096] bf16, WG/WU [14336][4096] bf16 (n-major), Hout[8192][14336]
// BM=256 BN=128 BK=64; 8 waves (2x4): per-wave 128 rows x 32 cols x {G,U}.
// Staging 2 ops/phase: P0:G(kt+1), P1:U(kt+1), P2:Alate(kt+1), P3:Aearly(kt+2).
// R12 ledger (matches k_gemm_down's 2 waits/tile; in-order retirement audit):
//   P1-end vmcnt(6): retires Alate(kt)   -> covers P2's A-hi reads.
//   P3-end vmcnt(4): retires Aearly(kt+1),G(kt+1),U(kt+1)
//                    -> covers next tile's P0 (A-lo+G) and P1 (U) reads.
//   Tails: P1-end 6->0 @kt=NKT-1; P3-end 4->2 @kt=NKT-2, skip @NKT-1.
// (R4 had a third wait at P0-end; it was redundant -- its coverage target
//  G/U(kt) is already retired by P3-end(kt-1) -- and cost one extra global-
//  latency stall per tile for all 8 barrier-locked waves.)
__global__ __launch_bounds__(512, 2) void k_gemm_gu(
    const u16* __restrict__ X, const u16* __restrict__ WG,
    const u16* __restrict__ WU, u16* __restrict__ Hout) {
  __shared__ __align__(16) u16 lA[2][16384];  // 2 x 256 rows x 64 k
  __shared__ __align__(16) u16 lG[2][8192];   // 2 x 128 rows x 64 k
  __shared__ __align__(16) u16 lU[2][8192];
  const int NKT = 64;
  const int m0 = blockIdx.x * 256, n0 = blockIdx.y * 128;
  const int tid = threadIdx.x, lane = tid & 63, wave = tid >> 6;
  const int p = lane >> 4, r16 = lane & 15;
  const int wr = wave >> 2, wc = wave & 3;

  const int srow = tid >> 3;                       // 0..63
  const int skb = (((tid ^ (tid >> 3)) & 7) << 4); // pre-swizzled k-byte
  const char* baA = (const char*)X + (long)(m0 + srow) * 8192 + skb;
  const char* baG = (const char*)WG + (long)(n0 + srow) * 8192 + skb;
  const char* baU = (const char*)WU + (long)(n0 + srow) * 8192 + skb;

#define ISS_A(kt2, rb) \
  stage_op(baA + (long)(rb) * 8192 + (long)(kt2) * 128, lA[(kt2) & 1], rb, wave)
#define ISS_G(kt2, rb) \
  stage_op(baG + (long)(rb) * 8192 + (long)(kt2) * 128, lG[(kt2) & 1], rb, wave)
#define ISS_U(kt2, rb) \
  stage_op(baU + (long)(rb) * 8192 + (long)(kt2) * 128, lU[(kt2) & 1], rb, wave)

  f32x4 aG[8][2], aU[8][2];
  const f32x4 zero = {0.f, 0.f, 0.f, 0.f};
#pragma unroll
  for (int i = 0; i < 8; ++i)
#pragma unroll
    for (int j = 0; j < 2; ++j) {
      aG[i][j] = zero;
      aU[i][j] = zero;
    }

  // prologue (steady-state image): issue [Ae(0),G(0),U(0),Al(0),Ae(1)] = 10;
  // WAITV(4) retires Ae(0),G(0),U(0) -> in flight {Al(0), Ae(1)} = 4. ✓
  ISS_A(0, 0); ISS_A(0, 128);
  ISS_G(0, 0); ISS_G(0, 64);
  ISS_U(0, 0); ISS_U(0, 64);
  ISS_A(0, 64); ISS_A(0, 192);
  ISS_A(1, 0); ISS_A(1, 128);
  WAITV(4);
  SBAR();

  for (int kt = 0; kt < NKT; ++kt) {
    const int b = kt & 1;
    const u16* hA = lA[b];
    const u16* hG = lG[b];
    const u16* hU = lU[b];
    bf16x8 af[2][4], gf[2][2], uf[2][2];
    // ---- P0: read A(i0..3)+G; stage kt+1's G; MFMA aG i0..3 (no wait) ----
#pragma unroll
    for (int ks = 0; ks < 2; ++ks) {
#pragma unroll
      for (int ii = 0; ii < 4; ++ii)
        af[ks][ii] = fragK(hA, wr * 128 + ii * 16 + r16, ks, p);
#pragma unroll
      for (int j = 0; j < 2; ++j)
        gf[ks][j] = fragK(hG, wc * 32 + j * 16 + r16, ks, p);
    }
    if (kt < NKT - 1) { ISS_G(kt + 1, 0); ISS_G(kt + 1, 64); }
    SBAR();
    WAIT_LGKM0();
    SETPRIO(1);
#pragma unroll
    for (int ks = 0; ks < 2; ++ks)
#pragma unroll
      for (int ii = 0; ii < 4; ++ii)
#pragma unroll
        for (int j = 0; j < 2; ++j)
          aG[ii][j] = MFMA16(af[ks][ii], gf[ks][j], aG[ii][j]);
    SETPRIO(0);
    SBAR();
    // ---- P1: read U; stage kt+1's U; MFMA aU i0..3; P1-end wait ----
#pragma unroll
    for (int ks = 0; ks < 2; ++ks)
#pragma unroll
      for (int j = 0; j < 2; ++j)
        uf[ks][j] = fragK(hU, wc * 32 + j * 16 + r16, ks, p);
    if (kt < NKT - 1) { ISS_U(kt + 1, 0); ISS_U(kt + 1, 64); }
    SBAR();
    WAIT_LGKM0();
    SETPRIO(1);
#pragma unroll
    for (int ks = 0; ks < 2; ++ks)
#pragma unroll
      for (int ii = 0; ii < 4; ++ii)
#pragma unroll
        for (int j = 0; j < 2; ++j)
          aU[ii][j] = MFMA16(af[ks][ii], uf[ks][j], aU[ii][j]);
    SETPRIO(0);
    if (kt < NKT - 1) WAITV(6); else WAITV(0);  // retire Alate(kt)
    SBAR();
    // ---- P2: read A(i4..7) (last read of buf b); stage kt+1's A-late ----
#pragma unroll
    for (int ks = 0; ks < 2; ++ks)
#pragma unroll
      for (int ii = 0; ii < 4; ++ii)
        af[ks][ii] = fragK(hA, wr * 128 + 64 + ii * 16 + r16, ks, p);
    if (kt < NKT - 1) { ISS_A(kt + 1, 64); ISS_A(kt + 1, 192); }
    SBAR();
    WAIT_LGKM0();
    SETPRIO(1);
#pragma unroll
    for (int ks = 0; ks < 2; ++ks)
#pragma unroll
      for (int ii = 0; ii < 4; ++ii)
#pragma unroll
        for (int j = 0; j < 2; ++j)
          aG[4 + ii][j] = MFMA16(af[ks][ii], gf[ks][j], aG[4 + ii][j]);
    SETPRIO(0);
    SBAR();
    // ---- P3: stage kt+2's A-early into buf b (reads drained); MFMA aU;
    //      P3-end wait ----
    if (kt < NKT - 2) { ISS_A(kt + 2, 0); ISS_A(kt + 2, 128); }
    SBAR();
    SETPRIO(1);
#pragma unroll
    for (int ks = 0; ks < 2; ++ks)
#pragma unroll
      for (int ii = 0; ii < 4; ++ii)
#pragma unroll
        for (int j = 0; j < 2; ++j)
          aU[4 + ii][j] = MFMA16(af[ks][ii], uf[ks][j], aU[4 + ii][j]);
    SETPRIO(0);
    if (kt < NKT - 2) WAITV(4);       // retire Aearly(kt+1),G(kt+1),U(kt+1)
    else if (kt == NKT - 2) WAITV(2);
    SBAR();
  }
#undef ISS_A
#undef ISS_G
#undef ISS_U

  // epilogue: silu(g)*u -> bf16. C/D map: col=lane&15, row=(lane>>4)*4+reg.
#pragma unroll
  for (int i = 0; i < 8; ++i) {
    const int row = m0 + wr * 128 + i * 16 + p * 4;
#pragma unroll
    for (int j = 0; j < 2; ++j) {
      const int col = n0 + wc * 32 + j * 16 + r16;
      u16* dst = Hout + (size_t)row * 14336 + col;
#pragma unroll
      for (int r = 0; r < 4; ++r) {
        const float gv = aG[i][j][r], uv = aU[i][j][r];
        const float sv = gv / (1.f + __expf(-gv)) * uv;
        dst[(size_t)r * 14336] = f32_to_bf16(sv);
      }
    }
  }
}

// ---------- down GEMM, R4-exact 4-phase fine-interleaved: out = h @ Wd -----
// Hin[8192][14336] bf16, WD[4096][14336] bf16 (n-major), Out[8192][4096] f32
// BM=BN=256 BK=64; 8 waves (2x4): per-wave 128 rows x 64 cols.
__global__ __launch_bounds__(512, 2) void k_gemm_down(
    const u16* __restrict__ Hin, const u16* __restrict__ WD,
    float* __restrict__ Out) {
  __shared__ __align__(16) u16 lA[2][16384];
  __shared__ __align__(16) u16 lB[2][16384];
  const int NKT = 224;
  const int m0 = blockIdx.x * 256, n0 = blockIdx.y * 256;
  const int tid = threadIdx.x, lane = tid & 63, wave = tid >> 6;
  const int p = lane >> 4, r16 = lane & 15;
  const int wr = wave >> 2, wc = wave & 3;

  const int srow = tid >> 3;
  const int skb = (((tid ^ (tid >> 3)) & 7) << 4);
  const char* baA = (const char*)Hin + (long)(m0 + srow) * 28672 + skb;
  const char* baB = (const char*)WD + (long)(n0 + srow) * 28672 + skb;

#define ISS_A(kt2, rb) \
  stage_op(baA + (long)(rb) * 28672 + (long)(kt2) * 128, lA[(kt2) & 1], rb, wave)
#define ISS_B(kt2, rb) \
  stage_op(baB + (long)(rb) * 28672 + (long)(kt2) * 128, lB[(kt2) & 1], rb, wave)

  f32x4 acc[8][4];
  const f32x4 zero = {0.f, 0.f, 0.f, 0.f};
#pragma unroll
  for (int i = 0; i < 8; ++i)
#pragma unroll
    for (int j = 0; j < 4; ++j) acc[i][j] = zero;

  // prologue: kt0's 8 in consumed order + kt1's first pair; vmcnt(4)
  ISS_A(0, 0); ISS_A(0, 128); ISS_B(0, 0); ISS_B(0, 64);
  ISS_B(0, 128); ISS_B(0, 192); ISS_A(0, 64); ISS_A(0, 192);
  ISS_A(1, 0); ISS_A(1, 128);
  WAITV(4);
  SBAR();

  for (int kt = 0; kt < NKT; ++kt) {
    const int b = kt & 1;
    const u16* hA = lA[b];
    const u16* hB = lB[b];
    bf16x8 af[2][4], bfr[2][4];
    // ---- P0: read A(i0..3)+B(j0..1); stage kt+1's B-early ----
#pragma unroll
    for (int ks = 0; ks < 2; ++ks) {
#pragma unroll
      for (int ii = 0; ii < 4; ++ii)
        af[ks][ii] = fragK(hA, wr * 128 + ii * 16 + r16, ks, p);
#pragma unroll
      for (int j = 0; j < 2; ++j)
        bfr[ks][j] = fragK(hB, wc * 64 + j * 16 + r16, ks, p);
    }
    if (kt < NKT - 1) { ISS_B(kt + 1, 0); ISS_B(kt + 1, 64); }
    SBAR();
    WAIT_LGKM0();
    SETPRIO(1);
#pragma unroll
    for (int ks = 0; ks < 2; ++ks)
#pragma unroll
      for (int ii = 0; ii < 4; ++ii)
#pragma unroll
        for (int j = 0; j < 2; ++j)
          acc[ii][j] = MFMA16(af[ks][ii], bfr[ks][j], acc[ii][j]);
    SETPRIO(0);
    SBAR();
    // ---- P1: read B(j2..3); stage kt+1's B-late ----
#pragma unroll
    for (int ks = 0; ks < 2; ++ks)
#pragma unroll
      for (int j = 2; j < 4; ++j)
        bfr[ks][j] = fragK(hB, wc * 64 + j * 16 + r16, ks, p);
    if (kt < NKT - 1) { ISS_B(kt + 1, 128); ISS_B(kt + 1, 192); }
    SBAR();
    WAIT_LGKM0();
    SETPRIO(1);
#pragma unroll
    for (int ks = 0; ks < 2; ++ks)
#pragma unroll
      for (int ii = 0; ii < 4; ++ii)
#pragma unroll
        for (int j = 2; j < 4; ++j)
          acc[ii][j] = MFMA16(af[ks][ii], bfr[ks][j], acc[ii][j]);
    SETPRIO(0);
    if (kt < NKT - 1) WAITV(6); else WAITV(0);  // kt's A64/A192 landed
    SBAR();
    // ---- P2: read A(i4..7) (last read of buf b); stage kt+1's A-late ----
#pragma unroll
    for (int ks = 0; ks < 2; ++ks)
#pragma unroll
      for (int ii = 0; ii < 4; ++ii)
        af[ks][ii] = fragK(hA, wr * 128 + 64 + ii * 16 + r16, ks, p);
    if (kt < NKT - 1) { ISS_A(kt + 1, 64); ISS_A(kt + 1, 192); }
    SBAR();
    WAIT_LGKM0();
    SETPRIO(1);
#pragma unroll
    for (int ks = 0; ks < 2; ++ks)
#pragma unroll
      for (int ii = 0; ii < 4; ++ii)
#pragma unroll
        for (int j = 0; j < 2; ++j)
          acc[4 + ii][j] = MFMA16(af[ks][ii], bfr[ks][j], acc[4 + ii][j]);
    SETPRIO(0);
    SBAR();
    // ---- P3: stage kt+2's A-early into buf b; MFMA i4..7 x j2..3 ----
    if (kt < NKT - 2) { ISS_A(kt + 2, 0); ISS_A(kt + 2, 128); }
    SBAR();
    SETPRIO(1);
#pragma unroll
    for (int ks = 0; ks < 2; ++ks)
#pragma unroll
      for (int ii = 0; ii < 4; ++ii)
#pragma unroll
        for (int j = 2; j < 4; ++j)
          acc[4 + ii][j] = MFMA16(af[ks][ii], bfr[ks][j], acc[4 + ii][j]);
    SETPRIO(0);
    if (kt < NKT - 2) WAITV(4);       // kt+1's first 6 landed
    else if (kt == NKT - 2) WAITV(2);
    SBAR();
  }
#undef ISS_A
#undef ISS_B

#pragma unroll
  for (int i = 0; i < 8; ++i) {
    const int row = m0 + wr * 128 + i * 16 + p * 4;
#pragma unroll
    for (int j = 0; j < 4; ++j) {
      const int col = n0 + wc * 64 + j * 16 + r16;
      float* dst = Out + (size_t)row * 4096 + col;
#pragma unroll
      for (int r = 0; r < 4; ++r) dst[(size_t)r * 4096] = acc[i][j][r];
    }
  }
}

// ---------- sentinel fill (ws too small diagnostic) ----------
__global__ void k_fill(float* o, long n, float v) {
  const long i = (long)blockIdx.x * 256 + threadIdx.x;
  if (i < n) o[i] = v;
}

extern "C" void kernel_launch(void* const* d_in, const int* in_sizes, int n_in,
                              void* d_out, int out_size, void* d_ws,
                              size_t ws_size, hipStream_t stream) {
  const float* x = (const float*)d_in[0];
  const int* gw = (const int*)d_in[1];
  const int* gz = (const int*)d_in[2];
  const float* gs = (const float*)d_in[3];
  const int* uw = (const int*)d_in[4];
  const int* uz = (const int*)d_in[5];
  const float* us = (const float*)d_in[6];
  const int* dw = (const int*)d_in[7];
  const int* dz = (const int*)d_in[8];
  const float* dsc = (const float*)d_in[9];
  float* out = (float*)d_out;

  const size_t NX = 33554432UL, NW = 58720256UL;
  const size_t need = 2UL * (NX + 3UL * NW + 117440512UL);
  if (ws_size < need) {
    k_fill<<<(out_size + 255) / 256, 256, 0, stream>>>(out, out_size, 1.0e6f);
    return;
  }
  u16* wsx = (u16*)d_ws;
  u16* wgq = wsx + NX;
  u16* wuq = wgq + NW;
  u16* wdq = wuq + NW;
  u16* wh = wdq + NW;

  k_convert_x<<<16384, 256, 0, stream>>>(x, wsx);
  dim3 dq1(64, 56);
  k_dequant<<<dq1, 256, 0, stream>>>(gw, gz, gs, wgq, 4096, 14336);
  k_dequant<<<dq1, 256, 0, stream>>>(uw, uz, us, wuq, 4096, 14336);
  dim3 dq2(224, 16);
  k_dequant<<<dq2, 256, 0, stream>>>(dw, dz, dsc, wdq, 14336, 4096);
  dim3 g1(32, 112);
  k_gemm_gu<<<g1, 512, 0, stream>>>(wsx, wgq, wuq, wh);
  dim3 g2(32, 16);
  k_gemm_down<<<g2, 512, 0, stream>>>(wh, wdq, out);
}